// Round 5
// baseline (2323.335 us; speedup 1.0000x reference)
//
#include <hip/hip_runtime.h>
#include <hip/hip_bf16.h>
#include <stdint.h>

// Problem constants (fixed by the reference)
#define HEADS 4
#define KNN   32
#define NKEYS 128
#define KDIM  256
#define VDIM  768
#define INDIM 3072
#define HALFD 128
#define NC    (VDIM + HEADS * KDIM)   // 1792 combined output cols: [dense(768) | scores(1024)]

typedef __bf16 bf16x8 __attribute__((ext_vector_type(8)));
typedef short  short8 __attribute__((ext_vector_type(8)));
typedef float  f32x4  __attribute__((ext_vector_type(4)));

__device__ __forceinline__ void async_copy16(const void* g, void* l) {
    __builtin_amdgcn_global_load_lds((__attribute__((address_space(1))) void*)(g),
                                     (__attribute__((address_space(3))) void*)(l),
                                     16, 0, 0);
}

__device__ __forceinline__ float bf2f(unsigned short h) {
    union { unsigned int u; float f; } c; c.u = ((unsigned int)h) << 16; return c.f;
}

// Staircase candidate table: {(i,j) : (i+1)*(j+1) <= 32} in flat-index order.
// Monotone-matrix argument: any (i,j) outside has >= 32 dominators that all
// precede it in JAX's tie-break order => true top-32 is inside. 119 entries.
#define NCAND 119
struct CandT { unsigned char ii[128]; unsigned char jj[128]; };
static constexpr CandT make_cands() {
    CandT t{}; int c = 0;
    for (int i = 0; i < 32; ++i)
        for (int j = 0; (i + 1) * (j + 1) <= 32; ++j) {
            t.ii[c] = (unsigned char)i; t.jj[c] = (unsigned char)j; ++c;
        }
    for (; c < 128; ++c) { t.ii[c] = 0; t.jj[c] = 0; }
    return t;
}
static constexpr CandT CAND = make_cands();

// ---------------------------------------------------------------------------
// Kernel 0: fp32 -> bf16 convert (one thread per 8 elements). Used for x and
// for the values table.
// ---------------------------------------------------------------------------
__global__ __launch_bounds__(256) void convert_bf16(
    const float* __restrict__ in, __hip_bfloat16* __restrict__ out, int n8)
{
    int i = blockIdx.x * 256 + threadIdx.x;
    if (i >= n8) return;
    float4 a = ((const float4*)in)[2 * i + 0];
    float4 b = ((const float4*)in)[2 * i + 1];
    union { short8 v; __hip_bfloat16 h[8]; } u;
    u.h[0] = __float2bfloat16(a.x); u.h[1] = __float2bfloat16(a.y);
    u.h[2] = __float2bfloat16(a.z); u.h[3] = __float2bfloat16(a.w);
    u.h[4] = __float2bfloat16(b.x); u.h[5] = __float2bfloat16(b.y);
    u.h[6] = __float2bfloat16(b.z); u.h[7] = __float2bfloat16(b.w);
    ((short8*)out)[i] = u.v;
}

// ---------------------------------------------------------------------------
// Kernel 1: build Wc rows 0..767 = W_dense^T as bf16, via LDS tiles
// ---------------------------------------------------------------------------
__global__ __launch_bounds__(256) void transpose_w(
    const float* __restrict__ Wd,   // (3072, 768) fp32
    __hip_bfloat16* __restrict__ Wc)// (1792, 3072) bf16
{
    __shared__ float tile[32][33];
    const int kt = blockIdx.x * 32;
    const int nt = blockIdx.y * 32;     // < 768 (dense only)
    const int tx = threadIdx.x;   // 0..31
    const int ty = threadIdx.y;   // 0..7
#pragma unroll
    for (int j = 0; j < 32; j += 8)
        tile[ty + j][tx] = Wd[(size_t)(kt + ty + j) * VDIM + nt + tx];
    __syncthreads();
#pragma unroll
    for (int j = 0; j < 32; j += 8)
        Wc[(size_t)(nt + ty + j) * INDIM + kt + tx] = __float2bfloat16(tile[tx][ty + j]);
}

// ---------------------------------------------------------------------------
// Kernel 1b: Wc rows 768..1791 = (W_q_slice @ keys^T)^T as bf16.
// Folds the PKM key projection into the GEMM weights:
//   Wc[768 + hh*128 + n, d] = sum_k W_q[d, hh*128 + k] * keys[hh, n, k]
// Grid: (INDIM/32, 8); block 256. ~0.4 GFLOP total.
// ---------------------------------------------------------------------------
__global__ __launch_bounds__(256) void prep_ws(
    const float* __restrict__ Wq,   // (3072, 1024) fp32
    const float* __restrict__ keys, // (4,2,128,128) fp32 == (8,128,128)
    __hip_bfloat16* __restrict__ Wc)// (1792, 3072) bf16
{
    const int hh = blockIdx.y;            // h*2+half, 0..7
    const int d0 = blockIdx.x * 32;
    const int qbase = hh * HALFD;         // col offset into Wq
    const int tid = threadIdx.x;
    __shared__ __align__(16) float wt[32][128];   // Wq tile [d][k], 16 KB

    // stage Wq tile: thread -> row (tid>>3), 16 consecutive cols
    {
        const int r = tid >> 3;
        const int c = (tid & 7) * 16;
        const float4* src = (const float4*)(Wq + (size_t)(d0 + r) * (HEADS * KDIM) + qbase + c);
        float4* dst = (float4*)&wt[r][c];
#pragma unroll
        for (int j = 0; j < 4; ++j) dst[j] = src[j];
    }
    __syncthreads();

    const int n  = tid & 127;
    const int dh = tid >> 7;              // 0 or 1: which 16-row group
    const float* krow = keys + (size_t)(hh * NKEYS + n) * HALFD;

    float acc[16];
#pragma unroll
    for (int r = 0; r < 16; ++r) acc[r] = 0.f;

    for (int k = 0; k < HALFD; k += 4) {
        float4 kv = *(const float4*)(krow + k);
#pragma unroll
        for (int r = 0; r < 16; ++r) {
            float4 wv = *(const float4*)&wt[dh * 16 + r][k];
            acc[r] = fmaf(wv.x, kv.x, acc[r]);
            acc[r] = fmaf(wv.y, kv.y, acc[r]);
            acc[r] = fmaf(wv.z, kv.z, acc[r]);
            acc[r] = fmaf(wv.w, kv.w, acc[r]);
        }
    }

    __hip_bfloat16* dst = Wc + (size_t)(VDIM + hh * NKEYS + n) * INDIM + d0 + dh * 16;
    union { short8 v; __hip_bfloat16 h[8]; } u0, u1;
#pragma unroll
    for (int r = 0; r < 8; ++r) { u0.h[r] = __float2bfloat16(acc[r]); u1.h[r] = __float2bfloat16(acc[8 + r]); }
    ((short8*)dst)[0] = u0.v;
    ((short8*)dst)[1] = u1.v;
}

// ---------------------------------------------------------------------------
// Kernel 1c: score bias sb[col] = b_q_slice . keys_row  (1024 elements, tiny)
// ---------------------------------------------------------------------------
__global__ __launch_bounds__(256) void prep_sbias(
    const float* __restrict__ bq,   // (1024,)
    const float* __restrict__ keys, // (8,128,128)
    float* __restrict__ sb)         // (1024,)
{
    const int col = blockIdx.x * 256 + threadIdx.x;
    const int hh = col >> 7, n = col & 127;
    const float* krow = keys + (size_t)(hh * NKEYS + n) * HALFD;
    const float* b = bq + hh * HALFD;
    float a = 0.f;
#pragma unroll 4
    for (int k = 0; k < HALFD; ++k) a = fmaf(b[k], krow[k], a);
    sb[col] = a;
}

// ---------------------------------------------------------------------------
// Kernel 2: C(M x 1792) = A(M x 3072) @ Bt^T + bias   (bf16 MFMA, m97 structure)
// Cols 0..767 = dense + b_dense; cols 768..1791 = PKM scores + score-bias.
// ---------------------------------------------------------------------------
__global__ __launch_bounds__(256) void gemm_bt(
    const __hip_bfloat16* __restrict__ A,   // (M, 3072) bf16
    const __hip_bfloat16* __restrict__ Bt,  // (1792, 3072) bf16
    const float* __restrict__ bd,  // (768,) fp32
    const float* __restrict__ sb,  // (1024,) fp32 score bias
    float* __restrict__ C, int M)
{
    constexpr int K = INDIM, N = NC;
    __shared__ __align__(16) __hip_bfloat16 As[128 * 32];
    __shared__ __align__(16) __hip_bfloat16 Bs[128 * 32];
    const int tid  = threadIdx.x;
    const int wave = tid >> 6, lane = tid & 63;
    const int wm = wave >> 1, wn = wave & 1;
    const int row0 = blockIdx.x * 128, col0 = blockIdx.y * 128;

    const int fb0 = (wave * 2 + 0) * 1024;
    const int fb1 = (wave * 2 + 1) * 1024;
    const int r0  = (fb0 >> 6) + (lane >> 2);
    const int r1  = (fb1 >> 6) + (lane >> 2);
    const int ce  = (lane & 3) * 8;
    const __hip_bfloat16* gA0 = A  + (size_t)(row0 + r0) * K + ce;
    const __hip_bfloat16* gA1 = A  + (size_t)(row0 + r1) * K + ce;
    const __hip_bfloat16* gB0 = Bt + (size_t)(col0 + r0) * K + ce;
    const __hip_bfloat16* gB1 = Bt + (size_t)(col0 + r1) * K + ce;
    char* lA0 = (char*)As + fb0;  char* lA1 = (char*)As + fb1;
    char* lB0 = (char*)Bs + fb0;  char* lB1 = (char*)Bs + fb1;

    const int aoff = (wm * 64 + (lane & 15)) * 64 + (lane >> 4) * 16;
    const int boff = (wn * 64 + (lane & 15)) * 64 + (lane >> 4) * 16;

    f32x4 acc[4][4];
#pragma unroll
    for (int i = 0; i < 4; i++)
#pragma unroll
        for (int j = 0; j < 4; j++) acc[i][j] = (f32x4){0.f, 0.f, 0.f, 0.f};

    for (int k0 = 0; k0 < K; k0 += 32) {
        __syncthreads();
        async_copy16(gA0 + k0, lA0);
        async_copy16(gA1 + k0, lA1);
        async_copy16(gB0 + k0, lB0);
        async_copy16(gB1 + k0, lB1);
        __syncthreads();

        bf16x8 af[4], bfr[4];
#pragma unroll
        for (int i = 0; i < 4; i++)
            af[i] = *(const bf16x8*)((const char*)As + aoff + i * 1024);
#pragma unroll
        for (int j = 0; j < 4; j++)
            bfr[j] = *(const bf16x8*)((const char*)Bs + boff + j * 1024);
#pragma unroll
        for (int i = 0; i < 4; i++)
#pragma unroll
            for (int j = 0; j < 4; j++)
                acc[i][j] = __builtin_amdgcn_mfma_f32_16x16x32_bf16(af[i], bfr[j], acc[i][j], 0, 0, 0);
    }

    float bias[4]; int ncol[4];
#pragma unroll
    for (int j = 0; j < 4; j++) {
        int n = col0 + wn * 64 + j * 16 + (lane & 15);
        ncol[j] = n;
        bias[j] = (n < VDIM) ? bd[n] : sb[n - VDIM];
    }
#pragma unroll
    for (int i = 0; i < 4; i++) {
#pragma unroll
        for (int r = 0; r < 4; r++) {
            int m = row0 + wm * 64 + i * 16 + (lane >> 4) * 4 + r;
            float* crow = C + (size_t)m * N;
#pragma unroll
            for (int j = 0; j < 4; j++) crow[ncol[j]] = acc[i][j][r] + bias[j];
        }
    }
}

// ---------------------------------------------------------------------------
// Kernel 3: FUSED rank-based top-k + softmax + value gather + dense +
// residual + layernorm. One block per token; wave h handles head h in the
// selection phase; all 256 threads cooperate in the gather/LN phase.
// __launch_bounds__(256, 8): force <=64 VGPR so 8 blocks (32 waves) fit per
// CU — round-4 counters showed VGPR=72 capped residency at 35% and starved
// the gather phase (2.07 TB/s vs the 3.9 TB/s this access pattern achieves
// at 90% occupancy).
// ---------------------------------------------------------------------------
__global__ __launch_bounds__(256, 8) void pkm_fuse_ln(
    const float* __restrict__ qd,              // (M, 1792): dense | scores
    const float* __restrict__ resid,           // (M, 768) fp32
    const unsigned short* __restrict__ vb,     // (16384, 768) bf16 bits
    const float* __restrict__ gamma, const float* __restrict__ beta,
    float* __restrict__ out)
{
    const int t = blockIdx.x;
    const int tid = threadIdx.x;
    const int h = tid >> 6, lane = tid & 63;

    __shared__ __align__(16) float sc[HEADS][2][NKEYS];     // 4 KB scores
    __shared__ float vsort[HEADS][2][KNN];                  // sorted top-32 vals
    __shared__ int   isort[HEADS][2][KNN];                  // sorted top-32 idxs
    __shared__ __align__(16) float csum[HEADS][128];        // candidate sums
    __shared__ float wsel[HEADS][KNN];                      // selected scores -> weights
    __shared__ int   osel[HEADS][KNN];                      // selected row offsets (elems)
    __shared__ float red[8];

    // ---- stage scores (1024 floats, one float4 per thread)
    {
        const float4* qrow = (const float4*)(qd + (size_t)t * NC + VDIM);
        ((float4*)sc)[tid] = qrow[tid];
    }
    __syncthreads();

    // ---- stage 1: rank-select top-32 of 128 per half (ties -> lower index,
    //      exactly jax.lax.top_k order); scatter into sorted lists.
    const int n0 = lane, n1 = lane + 64;
#pragma unroll
    for (int half = 0; half < 2; ++half) {
        const float4* scv = (const float4*)&sc[h][half][0];
        const float a0 = sc[h][half][n0];
        const float a1 = sc[h][half][n1];
        int r0 = 0, r1 = 0;
#pragma unroll
        for (int g4 = 0; g4 < 32; ++g4) {
            float4 e = scv[g4];                       // broadcast read
            int gb = g4 * 4;
            r0 += (e.x > a0) || (e.x == a0 && (gb + 0) < n0);
            r0 += (e.y > a0) || (e.y == a0 && (gb + 1) < n0);
            r0 += (e.z > a0) || (e.z == a0 && (gb + 2) < n0);
            r0 += (e.w > a0) || (e.w == a0 && (gb + 3) < n0);
            r1 += (e.x > a1) || (e.x == a1 && (gb + 0) < n1);
            r1 += (e.y > a1) || (e.y == a1 && (gb + 1) < n1);
            r1 += (e.z > a1) || (e.z == a1 && (gb + 2) < n1);
            r1 += (e.w > a1) || (e.w == a1 && (gb + 3) < n1);
        }
        if (r0 < KNN) { vsort[h][half][r0] = a0; isort[h][half][r0] = n0; }
        if (r1 < KNN) { vsort[h][half][r1] = a1; isort[h][half][r1] = n1; }
    }
    __syncthreads();

    // ---- stage 2: staircase candidates (sorted lists => exact top-32 superset)
    const int c0 = lane, c1 = lane + 64;
    float s0, s1 = -1e30f;
    int b0, b1 = 0;
    {
        int i0 = CAND.ii[c0], j0 = CAND.jj[c0];
        s0 = vsort[h][0][i0] + vsort[h][1][j0];
        b0 = isort[h][0][i0] * NKEYS + isort[h][1][j0];
    }
    if (c1 < NCAND) {
        int i1 = CAND.ii[c1], j1 = CAND.jj[c1];
        s1 = vsort[h][0][i1] + vsort[h][1][j1];
        b1 = isort[h][0][i1] * NKEYS + isort[h][1][j1];
    }
    csum[h][c0] = s0;
    csum[h][c1] = s1;
    __syncthreads();

    // rank among 128 candidates (ties -> lower candidate index == lower flat idx)
    {
        const float4* cs4 = (const float4*)&csum[h][0];
        int r0 = 0, r1 = 0;
#pragma unroll
        for (int g4 = 0; g4 < 32; ++g4) {
            float4 e = cs4[g4];
            int gb = g4 * 4;
            r0 += (e.x > s0) || (e.x == s0 && (gb + 0) < c0);
            r0 += (e.y > s0) || (e.y == s0 && (gb + 1) < c0);
            r0 += (e.z > s0) || (e.z == s0 && (gb + 2) < c0);
            r0 += (e.w > s0) || (e.w == s0 && (gb + 3) < c0);
            r1 += (e.x > s1) || (e.x == s1 && (gb + 0) < c1);
            r1 += (e.y > s1) || (e.y == s1 && (gb + 1) < c1);
            r1 += (e.z > s1) || (e.z == s1 && (gb + 2) < c1);
            r1 += (e.w > s1) || (e.w == s1 && (gb + 3) < c1);
        }
        // store element offset of the value row (b * VDIM) — removes the
        // per-iteration 64-bit multiply from the 128-deep gather loop.
        if (r0 < KNN) { wsel[h][r0] = s0; osel[h][r0] = b0 * VDIM; }
        if (r1 < KNN) { wsel[h][r1] = s1; osel[h][r1] = b1 * VDIM; }
    }
    __syncthreads();

    // ---- softmax over the 32 selected (lanes 0..31); overwrite wsel in place.
    // Within wave h, reads precede writes in program order — no hazard.
    if (lane < KNN) {
        float v = wsel[h][lane];
        float mx = v;
#pragma unroll
        for (int m = 16; m >= 1; m >>= 1) mx = fmaxf(mx, __shfl_xor(mx, m));
        float e = expf(v - mx);
        float sum = e;
#pragma unroll
        for (int m = 16; m >= 1; m >>= 1) sum += __shfl_xor(sum, m);
        wsel[h][lane] = e / sum;
    }
    __syncthreads();

    // ---- gather + dense + residual + layernorm (all 256 threads)
    const float* drow = qd + (size_t)t * NC;
    const float* rrow = resid + (size_t)t * VDIM;
    const float* wflat = &wsel[0][0];
    const int*   oflat = &osel[0][0];
    float acc[3];
#pragma unroll
    for (int j = 0; j < 3; ++j) {
        int d = tid + j * 256;
        acc[j] = drow[d] + rrow[d];
    }
    for (int p = 0; p < HEADS * KNN; ++p) {
        float w = wflat[p];
        const unsigned short* vrow = vb + oflat[p];
        acc[0] = fmaf(w, bf2f(vrow[tid]),       acc[0]);
        acc[1] = fmaf(w, bf2f(vrow[tid + 256]), acc[1]);
        acc[2] = fmaf(w, bf2f(vrow[tid + 512]), acc[2]);
    }
    float s  = acc[0] + acc[1] + acc[2];
    float s2 = acc[0] * acc[0] + acc[1] * acc[1] + acc[2] * acc[2];
#pragma unroll
    for (int m = 1; m < 64; m <<= 1) { s += __shfl_xor(s, m); s2 += __shfl_xor(s2, m); }
    if (lane == 0) { red[h] = s; red[4 + h] = s2; }
    __syncthreads();
    s  = red[0] + red[1] + red[2] + red[3];
    s2 = red[4] + red[5] + red[6] + red[7];
    const float mu  = s * (1.f / VDIM);
    const float var = s2 * (1.f / VDIM) - mu * mu;
    const float inv = rsqrtf(var + 1e-12f);
#pragma unroll
    for (int j = 0; j < 3; ++j) {
        int d = tid + j * 256;
        out[(size_t)t * VDIM + d] = (acc[j] - mu) * inv * gamma[d] + beta[d];
    }
}

// ---------------------------------------------------------------------------
extern "C" void kernel_launch(void* const* d_in, const int* in_sizes, int n_in,
                              void* d_out, int out_size, void* d_ws, size_t ws_size,
                              hipStream_t stream) {
    const float* x      = (const float*)d_in[0];  // (B*S, 3072) fp32
    const float* resid  = (const float*)d_in[1];  // (B*S, 768)
    const float* Wd     = (const float*)d_in[2];  // (3072, 768)
    const float* bd     = (const float*)d_in[3];  // (768,)
    const float* Wq     = (const float*)d_in[4];  // (3072, 1024)
    const float* bq     = (const float*)d_in[5];  // (1024,)
    const float* keys   = (const float*)d_in[6];  // (4,2,128,128)
    const float* values = (const float*)d_in[7];  // (16384, 768)
    const float* gamma  = (const float*)d_in[8];
    const float* beta   = (const float*)d_in[9];
    float* out = (float*)d_out;                    // fp32 output

    const int M = in_sizes[0] / INDIM;   // 16384

    // workspace layout
    uint8_t* w = (uint8_t*)d_ws;
    const size_t szXb = (size_t)M * INDIM * sizeof(__hip_bfloat16);    // 100.7 MB
    const size_t szWc = (size_t)NC * INDIM * sizeof(__hip_bfloat16);   // 11.0 MB
    const size_t szQd = (size_t)M * NC * sizeof(float);                // 117.4 MB
    const size_t szSb = (size_t)(HEADS * KDIM) * sizeof(float);        // 4 KB
    if (szXb + szWc + szQd + szSb > ws_size) return;
    __hip_bfloat16* xb = (__hip_bfloat16*)w;           w += szXb;
    __hip_bfloat16* Wc = (__hip_bfloat16*)w;           w += szWc;
    float*          qd = (float*)w;                    w += szQd;
    float*          sb = (float*)w;                    w += szSb;

    // bf16 values table aliases the xb region (dead after gemm_bt; 25.2 MB
    // needed, 100.7 MB available). Stream order guarantees safety.
    __hip_bfloat16* vb = xb;

    const int n8 = (M * INDIM) / 8;
    convert_bf16<<<(n8 + 255) / 256, 256, 0, stream>>>(x, xb, n8);
    transpose_w<<<dim3(INDIM / 32, VDIM / 32), dim3(32, 8), 0, stream>>>(Wd, Wc);
    prep_ws<<<dim3(INDIM / 32, 2 * HEADS), 256, 0, stream>>>(Wq, keys, Wc);
    prep_sbias<<<(HEADS * KDIM) / 256, 256, 0, stream>>>(bq, keys, sb);
    gemm_bt<<<dim3(M / 128, NC / 128), 256, 0, stream>>>(xb, Wc, bd, sb, qd, M);

    const int nv8 = (16384 * VDIM) / 8;   // values: 16384 x 768
    convert_bf16<<<(nv8 + 255) / 256, 256, 0, stream>>>(values, vb, nv8);

    pkm_fuse_ln<<<M, 256, 0, stream>>>(qd, resid, (const unsigned short*)vb, gamma, beta, out);
}

// Round 6
// 1012.111 us; speedup vs baseline: 2.2955x; 2.2955x over previous
//
#include <hip/hip_runtime.h>
#include <hip/hip_bf16.h>
#include <stdint.h>

// Problem constants (fixed by the reference)
#define HEADS 4
#define KNN   32
#define NKEYS 128
#define KDIM  256
#define VDIM  768
#define INDIM 3072
#define HALFD 128
#define NC    (VDIM + HEADS * KDIM)   // 1792 combined output cols: [dense(768) | scores(1024)]

typedef __bf16 bf16x8 __attribute__((ext_vector_type(8)));
typedef short  short8 __attribute__((ext_vector_type(8)));
typedef float  f32x4  __attribute__((ext_vector_type(4)));
typedef unsigned long long u64;
typedef unsigned long long u64x2 __attribute__((ext_vector_type(2)));

__device__ __forceinline__ void async_copy16(const void* g, void* l) {
    __builtin_amdgcn_global_load_lds((__attribute__((address_space(1))) void*)(g),
                                     (__attribute__((address_space(3))) void*)(l),
                                     16, 0, 0);
}

__device__ __forceinline__ float bf2f(unsigned short h) {
    union { unsigned int u; float f; } c; c.u = ((unsigned int)h) << 16; return c.f;
}

// Monotone (order-preserving) map f32 -> u32: a > b  <=>  m(a) > m(b).
__device__ __forceinline__ unsigned fmono(float f) {
    unsigned u = __float_as_uint(f);
    return u ^ ((unsigned)(-(int)(u >> 31)) | 0x80000000u);
}

// Staircase candidate table: {(i,j) : (i+1)*(j+1) <= 32} in flat-index order.
// Monotone-matrix argument: any (i,j) outside has >= 32 dominators that all
// precede it in JAX's tie-break order => true top-32 is inside. 119 entries.
#define NCAND 119
struct CandT { unsigned char ii[128]; unsigned char jj[128]; };
static constexpr CandT make_cands() {
    CandT t{}; int c = 0;
    for (int i = 0; i < 32; ++i)
        for (int j = 0; (i + 1) * (j + 1) <= 32; ++j) {
            t.ii[c] = (unsigned char)i; t.jj[c] = (unsigned char)j; ++c;
        }
    for (; c < 128; ++c) { t.ii[c] = 0; t.jj[c] = 0; }
    return t;
}
static constexpr CandT CAND = make_cands();

// ---------------------------------------------------------------------------
// Kernel 0: fp32 -> bf16 convert (one thread per 8 elements). Used for x and
// for the values table.
// ---------------------------------------------------------------------------
__global__ __launch_bounds__(256) void convert_bf16(
    const float* __restrict__ in, __hip_bfloat16* __restrict__ out, int n8)
{
    int i = blockIdx.x * 256 + threadIdx.x;
    if (i >= n8) return;
    float4 a = ((const float4*)in)[2 * i + 0];
    float4 b = ((const float4*)in)[2 * i + 1];
    union { short8 v; __hip_bfloat16 h[8]; } u;
    u.h[0] = __float2bfloat16(a.x); u.h[1] = __float2bfloat16(a.y);
    u.h[2] = __float2bfloat16(a.z); u.h[3] = __float2bfloat16(a.w);
    u.h[4] = __float2bfloat16(b.x); u.h[5] = __float2bfloat16(b.y);
    u.h[6] = __float2bfloat16(b.z); u.h[7] = __float2bfloat16(b.w);
    ((short8*)out)[i] = u.v;
}

// ---------------------------------------------------------------------------
// Kernel 1: build Wc rows 0..767 = W_dense^T as bf16, via LDS tiles
// ---------------------------------------------------------------------------
__global__ __launch_bounds__(256) void transpose_w(
    const float* __restrict__ Wd,   // (3072, 768) fp32
    __hip_bfloat16* __restrict__ Wc)// (1792, 3072) bf16
{
    __shared__ float tile[32][33];
    const int kt = blockIdx.x * 32;
    const int nt = blockIdx.y * 32;     // < 768 (dense only)
    const int tx = threadIdx.x;   // 0..31
    const int ty = threadIdx.y;   // 0..7
#pragma unroll
    for (int j = 0; j < 32; j += 8)
        tile[ty + j][tx] = Wd[(size_t)(kt + ty + j) * VDIM + nt + tx];
    __syncthreads();
#pragma unroll
    for (int j = 0; j < 32; j += 8)
        Wc[(size_t)(nt + ty + j) * INDIM + kt + tx] = __float2bfloat16(tile[tx][ty + j]);
}

// ---------------------------------------------------------------------------
// Kernel 1b: Wc rows 768..1791 = (W_q_slice @ keys^T)^T as bf16.
// ---------------------------------------------------------------------------
__global__ __launch_bounds__(256) void prep_ws(
    const float* __restrict__ Wq,   // (3072, 1024) fp32
    const float* __restrict__ keys, // (4,2,128,128) fp32 == (8,128,128)
    __hip_bfloat16* __restrict__ Wc)// (1792, 3072) bf16
{
    const int hh = blockIdx.y;            // h*2+half, 0..7
    const int d0 = blockIdx.x * 32;
    const int qbase = hh * HALFD;         // col offset into Wq
    const int tid = threadIdx.x;
    __shared__ __align__(16) float wt[32][128];   // Wq tile [d][k], 16 KB

    {
        const int r = tid >> 3;
        const int c = (tid & 7) * 16;
        const float4* src = (const float4*)(Wq + (size_t)(d0 + r) * (HEADS * KDIM) + qbase + c);
        float4* dst = (float4*)&wt[r][c];
#pragma unroll
        for (int j = 0; j < 4; ++j) dst[j] = src[j];
    }
    __syncthreads();

    const int n  = tid & 127;
    const int dh = tid >> 7;              // 0 or 1: which 16-row group
    const float* krow = keys + (size_t)(hh * NKEYS + n) * HALFD;

    float acc[16];
#pragma unroll
    for (int r = 0; r < 16; ++r) acc[r] = 0.f;

    for (int k = 0; k < HALFD; k += 4) {
        float4 kv = *(const float4*)(krow + k);
#pragma unroll
        for (int r = 0; r < 16; ++r) {
            float4 wv = *(const float4*)&wt[dh * 16 + r][k];
            acc[r] = fmaf(wv.x, kv.x, acc[r]);
            acc[r] = fmaf(wv.y, kv.y, acc[r]);
            acc[r] = fmaf(wv.z, kv.z, acc[r]);
            acc[r] = fmaf(wv.w, kv.w, acc[r]);
        }
    }

    __hip_bfloat16* dst = Wc + (size_t)(VDIM + hh * NKEYS + n) * INDIM + d0 + dh * 16;
    union { short8 v; __hip_bfloat16 h[8]; } u0, u1;
#pragma unroll
    for (int r = 0; r < 8; ++r) { u0.h[r] = __float2bfloat16(acc[r]); u1.h[r] = __float2bfloat16(acc[8 + r]); }
    ((short8*)dst)[0] = u0.v;
    ((short8*)dst)[1] = u1.v;
}

// ---------------------------------------------------------------------------
// Kernel 1c: score bias sb[col] = b_q_slice . keys_row  (1024 elements, tiny)
// ---------------------------------------------------------------------------
__global__ __launch_bounds__(256) void prep_sbias(
    const float* __restrict__ bq,   // (1024,)
    const float* __restrict__ keys, // (8,128,128)
    float* __restrict__ sb)         // (1024,)
{
    const int col = blockIdx.x * 256 + threadIdx.x;
    const int hh = col >> 7, n = col & 127;
    const float* krow = keys + (size_t)(hh * NKEYS + n) * HALFD;
    const float* b = bq + hh * HALFD;
    float a = 0.f;
#pragma unroll 4
    for (int k = 0; k < HALFD; ++k) a = fmaf(b[k], krow[k], a);
    sb[col] = a;
}

// ---------------------------------------------------------------------------
// Kernel 2: C(M x 1792) = A(M x 3072) @ Bt^T + bias   (bf16 MFMA, m97 structure)
// ---------------------------------------------------------------------------
__global__ __launch_bounds__(256) void gemm_bt(
    const __hip_bfloat16* __restrict__ A,   // (M, 3072) bf16
    const __hip_bfloat16* __restrict__ Bt,  // (1792, 3072) bf16
    const float* __restrict__ bd,  // (768,) fp32
    const float* __restrict__ sb,  // (1024,) fp32 score bias
    float* __restrict__ C, int M)
{
    constexpr int K = INDIM, N = NC;
    __shared__ __align__(16) __hip_bfloat16 As[128 * 32];
    __shared__ __align__(16) __hip_bfloat16 Bs[128 * 32];
    const int tid  = threadIdx.x;
    const int wave = tid >> 6, lane = tid & 63;
    const int wm = wave >> 1, wn = wave & 1;
    const int row0 = blockIdx.x * 128, col0 = blockIdx.y * 128;

    const int fb0 = (wave * 2 + 0) * 1024;
    const int fb1 = (wave * 2 + 1) * 1024;
    const int r0  = (fb0 >> 6) + (lane >> 2);
    const int r1  = (fb1 >> 6) + (lane >> 2);
    const int ce  = (lane & 3) * 8;
    const __hip_bfloat16* gA0 = A  + (size_t)(row0 + r0) * K + ce;
    const __hip_bfloat16* gA1 = A  + (size_t)(row0 + r1) * K + ce;
    const __hip_bfloat16* gB0 = Bt + (size_t)(col0 + r0) * K + ce;
    const __hip_bfloat16* gB1 = Bt + (size_t)(col0 + r1) * K + ce;
    char* lA0 = (char*)As + fb0;  char* lA1 = (char*)As + fb1;
    char* lB0 = (char*)Bs + fb0;  char* lB1 = (char*)Bs + fb1;

    const int aoff = (wm * 64 + (lane & 15)) * 64 + (lane >> 4) * 16;
    const int boff = (wn * 64 + (lane & 15)) * 64 + (lane >> 4) * 16;

    f32x4 acc[4][4];
#pragma unroll
    for (int i = 0; i < 4; i++)
#pragma unroll
        for (int j = 0; j < 4; j++) acc[i][j] = (f32x4){0.f, 0.f, 0.f, 0.f};

    for (int k0 = 0; k0 < K; k0 += 32) {
        __syncthreads();
        async_copy16(gA0 + k0, lA0);
        async_copy16(gA1 + k0, lA1);
        async_copy16(gB0 + k0, lB0);
        async_copy16(gB1 + k0, lB1);
        __syncthreads();

        bf16x8 af[4], bfr[4];
#pragma unroll
        for (int i = 0; i < 4; i++)
            af[i] = *(const bf16x8*)((const char*)As + aoff + i * 1024);
#pragma unroll
        for (int j = 0; j < 4; j++)
            bfr[j] = *(const bf16x8*)((const char*)Bs + boff + j * 1024);
#pragma unroll
        for (int i = 0; i < 4; i++)
#pragma unroll
            for (int j = 0; j < 4; j++)
                acc[i][j] = __builtin_amdgcn_mfma_f32_16x16x32_bf16(af[i], bfr[j], acc[i][j], 0, 0, 0);
    }

    float bias[4]; int ncol[4];
#pragma unroll
    for (int j = 0; j < 4; j++) {
        int n = col0 + wn * 64 + j * 16 + (lane & 15);
        ncol[j] = n;
        bias[j] = (n < VDIM) ? bd[n] : sb[n - VDIM];
    }
#pragma unroll
    for (int i = 0; i < 4; i++) {
#pragma unroll
        for (int r = 0; r < 4; r++) {
            int m = row0 + wm * 64 + i * 16 + (lane >> 4) * 4 + r;
            float* crow = C + (size_t)m * N;
#pragma unroll
            for (int j = 0; j < 4; j++) crow[ncol[j]] = acc[i][j][r] + bias[j];
        }
    }
}

// ---------------------------------------------------------------------------
// Kernel 3: FUSED top-k + softmax + value gather + dense + residual + LN.
// u64 packed-key ranking: key = (monotone(f32) << 32) | (127 - idx) makes the
// rank predicate a single u64 compare while preserving exact jax.lax.top_k
// tie order (lower index wins among equal values). This halves rank-phase
// VALU and, more importantly, shrinks live state so the kernel fits in the
// <=64-VGPR class (8 waves/SIMD) WITHOUT spilling — round 5's forced squeeze
// at the old structure spilled ~1KB/thread (WRITE_SIZE 48MB -> 4.2GB).
// ---------------------------------------------------------------------------
__global__ __launch_bounds__(256, 8) void pkm_fuse_ln(
    const float* __restrict__ qd,              // (M, 1792): dense | scores
    const float* __restrict__ resid,           // (M, 768) fp32
    const unsigned short* __restrict__ vb,     // (16384, 768) bf16 bits
    const float* __restrict__ gamma, const float* __restrict__ beta,
    float* __restrict__ out)
{
    const int t = blockIdx.x;
    const int tid = threadIdx.x;
    const int h = tid >> 6, lane = tid & 63;

    __shared__ __align__(16) float sc[HEADS][2][NKEYS];     // 4 KB raw scores
    __shared__ __align__(16) u64   ku[HEADS][2][NKEYS];     // 8 KB packed keys
    __shared__ float vsort[HEADS][2][KNN];                  // sorted top-32 vals
    __shared__ int   isort[HEADS][2][KNN];                  // sorted top-32 idxs
    __shared__ __align__(16) u64   ck[HEADS][128];          // 4 KB candidate keys
    __shared__ float wsel[HEADS][KNN];                      // selected -> weights
    __shared__ int   osel[HEADS][KNN];                      // value row offsets
    __shared__ float red[8];

    // ---- stage scores + build packed keys in one pass (flat entry = tid*4+k)
    {
        const float4* qrow = (const float4*)(qd + (size_t)t * NC + VDIM);
        float4 v = qrow[tid];
        ((float4*)sc)[tid] = v;
        u64* kflat = &ku[0][0][0];
        float vv[4] = {v.x, v.y, v.z, v.w};
        const int e0 = tid * 4;
#pragma unroll
        for (int k = 0; k < 4; ++k) {
            const int e = e0 + k;
            const int n = e & (NKEYS - 1);
            kflat[e] = ((u64)fmono(vv[k]) << 32) | (unsigned)(NKEYS - 1 - n);
        }
    }
    __syncthreads();

    // ---- stage 1: rank-select top-32 of 128 per half via u64 keys.
    const int n0 = lane, n1 = lane + 64;
#pragma unroll
    for (int half = 0; half < 2; ++half) {
        const u64* kb = &ku[h][half][0];
        const u64x2* kv = (const u64x2*)kb;
        const u64 a0 = kb[n0], a1 = kb[n1];
        int r0 = 0, r1 = 0;
#pragma unroll 8
        for (int g = 0; g < 64; ++g) {
            u64x2 e = kv[g];                          // broadcast read
            r0 += (e[0] > a0); r0 += (e[1] > a0);
            r1 += (e[0] > a1); r1 += (e[1] > a1);
        }
        if (r0 < KNN) { vsort[h][half][r0] = sc[h][half][n0]; isort[h][half][r0] = n0; }
        if (r1 < KNN) { vsort[h][half][r1] = sc[h][half][n1]; isort[h][half][r1] = n1; }
    }
    __syncthreads();

    // ---- stage 2: staircase candidates; rank via u64 keys (tie -> lower c).
    const int c0 = lane, c1 = lane + 64;
    float s0f, s1f = 0.f;
    int b0, b1 = 0;
    u64 k0, k1 = 0;                                  // pad key 0 ranks last
    {
        const int i0 = CAND.ii[c0], j0 = CAND.jj[c0];
        s0f = vsort[h][0][i0] + vsort[h][1][j0];
        b0  = isort[h][0][i0] * NKEYS + isort[h][1][j0];
        k0  = ((u64)fmono(s0f) << 32) | (unsigned)(127 - c0);
    }
    if (c1 < NCAND) {
        const int i1 = CAND.ii[c1], j1 = CAND.jj[c1];
        s1f = vsort[h][0][i1] + vsort[h][1][j1];
        b1  = isort[h][0][i1] * NKEYS + isort[h][1][j1];
        k1  = ((u64)fmono(s1f) << 32) | (unsigned)(127 - c1);
    }
    ck[h][c0] = k0;
    ck[h][c1] = k1;
    __syncthreads();

    {
        const u64x2* cv = (const u64x2*)&ck[h][0];
        int r0 = 0, r1 = 0;
#pragma unroll 8
        for (int g = 0; g < 64; ++g) {
            u64x2 e = cv[g];
            r0 += (e[0] > k0); r0 += (e[1] > k0);
            r1 += (e[0] > k1); r1 += (e[1] > k1);
        }
        if (r0 < KNN) { wsel[h][r0] = s0f; osel[h][r0] = b0 * VDIM; }
        if (c1 < NCAND && r1 < KNN) { wsel[h][r1] = s1f; osel[h][r1] = b1 * VDIM; }
    }
    __syncthreads();

    // ---- softmax over the 32 selected (lanes 0..31); overwrite wsel in place.
    if (lane < KNN) {
        float v = wsel[h][lane];
        float mx = v;
#pragma unroll
        for (int m = 16; m >= 1; m >>= 1) mx = fmaxf(mx, __shfl_xor(mx, m));
        float e = expf(v - mx);
        float sum = e;
#pragma unroll
        for (int m = 16; m >= 1; m >>= 1) sum += __shfl_xor(sum, m);
        wsel[h][lane] = e / sum;
    }
    __syncthreads();

    // ---- gather + dense + residual + layernorm (all 256 threads)
    const float* drow = qd + (size_t)t * NC;
    const float* rrow = resid + (size_t)t * VDIM;
    const float* wflat = &wsel[0][0];
    const int*   oflat = &osel[0][0];
    float acc[3];
#pragma unroll
    for (int j = 0; j < 3; ++j) {
        int d = tid + j * 256;
        acc[j] = drow[d] + rrow[d];
    }
    for (int p = 0; p < HEADS * KNN; ++p) {
        float w = wflat[p];
        const unsigned short* vrow = vb + oflat[p];
        acc[0] = fmaf(w, bf2f(vrow[tid]),       acc[0]);
        acc[1] = fmaf(w, bf2f(vrow[tid + 256]), acc[1]);
        acc[2] = fmaf(w, bf2f(vrow[tid + 512]), acc[2]);
    }
    float s  = acc[0] + acc[1] + acc[2];
    float s2 = acc[0] * acc[0] + acc[1] * acc[1] + acc[2] * acc[2];
#pragma unroll
    for (int m = 1; m < 64; m <<= 1) { s += __shfl_xor(s, m); s2 += __shfl_xor(s2, m); }
    if (lane == 0) { red[h] = s; red[4 + h] = s2; }
    __syncthreads();
    s  = red[0] + red[1] + red[2] + red[3];
    s2 = red[4] + red[5] + red[6] + red[7];
    const float mu  = s * (1.f / VDIM);
    const float var = s2 * (1.f / VDIM) - mu * mu;
    const float inv = rsqrtf(var + 1e-12f);
#pragma unroll
    for (int j = 0; j < 3; ++j) {
        int d = tid + j * 256;
        out[(size_t)t * VDIM + d] = (acc[j] - mu) * inv * gamma[d] + beta[d];
    }
}

// ---------------------------------------------------------------------------
extern "C" void kernel_launch(void* const* d_in, const int* in_sizes, int n_in,
                              void* d_out, int out_size, void* d_ws, size_t ws_size,
                              hipStream_t stream) {
    const float* x      = (const float*)d_in[0];  // (B*S, 3072) fp32
    const float* resid  = (const float*)d_in[1];  // (B*S, 768)
    const float* Wd     = (const float*)d_in[2];  // (3072, 768)
    const float* bd     = (const float*)d_in[3];  // (768,)
    const float* Wq     = (const float*)d_in[4];  // (3072, 1024)
    const float* bq     = (const float*)d_in[5];  // (1024,)
    const float* keys   = (const float*)d_in[6];  // (4,2,128,128)
    const float* values = (const float*)d_in[7];  // (16384, 768)
    const float* gamma  = (const float*)d_in[8];
    const float* beta   = (const float*)d_in[9];
    float* out = (float*)d_out;                    // fp32 output

    const int M = in_sizes[0] / INDIM;   // 16384

    // workspace layout
    uint8_t* w = (uint8_t*)d_ws;
    const size_t szXb = (size_t)M * INDIM * sizeof(__hip_bfloat16);    // 100.7 MB
    const size_t szWc = (size_t)NC * INDIM * sizeof(__hip_bfloat16);   // 11.0 MB
    const size_t szQd = (size_t)M * NC * sizeof(float);                // 117.4 MB
    const size_t szSb = (size_t)(HEADS * KDIM) * sizeof(float);        // 4 KB
    if (szXb + szWc + szQd + szSb > ws_size) return;
    __hip_bfloat16* xb = (__hip_bfloat16*)w;           w += szXb;
    __hip_bfloat16* Wc = (__hip_bfloat16*)w;           w += szWc;
    float*          qd = (float*)w;                    w += szQd;
    float*          sb = (float*)w;                    w += szSb;

    // bf16 values table aliases the xb region (dead after gemm_bt; 25.2 MB
    // needed, 100.7 MB available). Stream order guarantees safety.
    __hip_bfloat16* vb = xb;

    const int n8 = (M * INDIM) / 8;
    convert_bf16<<<(n8 + 255) / 256, 256, 0, stream>>>(x, xb, n8);
    transpose_w<<<dim3(INDIM / 32, VDIM / 32), dim3(32, 8), 0, stream>>>(Wd, Wc);
    prep_ws<<<dim3(INDIM / 32, 2 * HEADS), 256, 0, stream>>>(Wq, keys, Wc);
    prep_sbias<<<(HEADS * KDIM) / 256, 256, 0, stream>>>(bq, keys, sb);
    gemm_bt<<<dim3(M / 128, NC / 128), 256, 0, stream>>>(xb, Wc, bd, sb, qd, M);

    const int nv8 = (16384 * VDIM) / 8;   // values: 16384 x 768
    convert_bf16<<<(nv8 + 255) / 256, 256, 0, stream>>>(values, vb, nv8);

    pkm_fuse_ln<<<M, 256, 0, stream>>>(qd, resid, (const unsigned short*)vb, gamma, beta, out);
}